// Round 6
// baseline (407.814 us; speedup 1.0000x reference)
//
#include <hip/hip_runtime.h>

typedef unsigned short u16;
typedef unsigned int   u32;
typedef __attribute__((ext_vector_type(4))) float  f32x4;
typedef __attribute__((ext_vector_type(8))) __bf16 bf16x8;
typedef __attribute__((ext_vector_type(4))) u32    u32x4;
typedef __attribute__((ext_vector_type(2))) u32    u32x2;

#define B_ 4
#define S_ 2048
#define E_ 512
#define H_ 8
#define D_ 64

__device__ __forceinline__ u16 f2bf(float f) {
  union { float f; u32 u; } a; a.f = f;
  u32 r = a.u + 0x7FFFu + ((a.u >> 16) & 1u);   // RNE
  return (u16)(r >> 16);
}
__device__ __forceinline__ float bf2f(u16 u) {
  union { u32 u; float f; } a; a.u = (u32)u << 16;
  return a.f;
}
__device__ __forceinline__ u32 pkbf(float lo, float hi) {  // bf16(lo) | bf16(hi)<<16
  u32 r;
  asm("v_cvt_pk_bf16_f32 %0, %1, %2" : "=v"(r) : "v"(lo), "v"(hi));
  return r;
}

// async global->LDS, 16B per lane; lds ptr wave-uniform (HW adds lane*16)
#define GLOAD16(gp, lp) __builtin_amdgcn_global_load_lds( \
    (const __attribute__((address_space(1))) void*)(gp),  \
    (__attribute__((address_space(3))) void*)(lp), 16, 0, 0)

// ---------------- weight fp32 -> bf16 convert ----------------
__global__ __launch_bounds__(256) void cvt_k(const float* __restrict__ s,
                                             u16* __restrict__ d, int n) {
  int i = (blockIdx.x * 256 + threadIdx.x) * 4;
  if (i >= n) return;
  f32x4 v = *(const f32x4*)(s + i);
  u32x2 o;
  o.x = pkbf(v[0], v[1]);
  o.y = pkbf(v[2], v[3]);
  *(u32x2*)(d + i) = o;
}

// ---------------- RoPE cos/sin table ----------------
__global__ __launch_bounds__(256) void ropetab_k(float* __restrict__ ct,
                                                 float* __restrict__ st) {
  int idx = blockIdx.x * 256 + threadIdx.x;   // S_*64 total
  int s = idx >> 6, j = idx & 63;
  float f = powf(10000.f, -(float)(j & 31) * (1.f / 32.f));
  float ang = (float)s * f;
  ct[idx] = cosf(ang);
  st[idx] = sinf(ang);
}

// ---------------- RMSNorm (row of 512), fp32 in -> bf16 out ----------------
__global__ __launch_bounds__(256) void rmsnorm_k(const float* __restrict__ x,
                                                 const float* __restrict__ wv,
                                                 u16* __restrict__ o) {
  const int row = blockIdx.x;
  const int t = threadIdx.x;
  const float* xr = x + (size_t)row * E_;
  float v0 = xr[t], v1 = xr[t + 256];
  float ss = v0 * v0 + v1 * v1;
#pragma unroll
  for (int m = 1; m < 64; m <<= 1) ss += __shfl_xor(ss, m, 64);
  __shared__ float red[4];
  if ((t & 63) == 0) red[t >> 6] = ss;
  __syncthreads();
  float tot = red[0] + red[1] + red[2] + red[3];
  float rms = 1.f / sqrtf(tot * (1.f / (float)E_) + 1e-6f);
  o[(size_t)row * E_ + t]       = f2bf(v0 * rms * wv[t]);
  o[(size_t)row * E_ + t + 256] = f2bf(v1 * rms * wv[t + 256]);
}

// ------------- column sums (xm) + batch sum/sumsq of h -------------
__global__ __launch_bounds__(256) void colsum_k(const u16* __restrict__ h,
                                                float* __restrict__ st) {
  const int b = blockIdx.x >> 3, ck = blockIdx.x & 7;
  const u16* hb = h + ((size_t)b * S_ + ck * 256) * E_;
  const int t = threadIdx.x;
  float a0 = 0, a1 = 0, s = 0, sq = 0;
  for (int r = 0; r < 256; ++r) {
    float v0 = bf2f(hb[(size_t)r * E_ + t]);
    float v1 = bf2f(hb[(size_t)r * E_ + t + 256]);
    a0 += v0; a1 += v1;
    s += v0 + v1; sq += v0 * v0 + v1 * v1;
  }
  atomicAdd(&st[8 + b * E_ + t], a0);
  atomicAdd(&st[8 + b * E_ + t + 256], a1);
#pragma unroll
  for (int m = 1; m < 64; m <<= 1) { s += __shfl_xor(s, m, 64); sq += __shfl_xor(sq, m, 64); }
  if ((t & 63) == 0) { atomicAdd(&st[b], s); atomicAdd(&st[4 + b], sq); }
}

// ------------- complexity -> window size scalar -------------
__global__ __launch_bounds__(128) void wscalc_k(float* __restrict__ st,
                                                const float* __restrict__ w1,
                                                const float* __restrict__ w2) {
  const int j = threadIdx.x;
  __shared__ float comp[4];
  __shared__ float tw[2];
  float dot[4] = {0.f, 0.f, 0.f, 0.f};
  const float* w1r = w1 + (size_t)j * E_;
  for (int e = 0; e < E_; ++e) {
    float wv = w1r[e];
    dot[0] += st[8 + 0 * E_ + e] * wv;
    dot[1] += st[8 + 1 * E_ + e] * wv;
    dot[2] += st[8 + 2 * E_ + e] * wv;
    dot[3] += st[8 + 3 * E_ + e] * wv;
  }
  for (int b = 0; b < 4; ++b) {
    float d = dot[b] * (1.f / (float)S_);
    float si = d / (1.f + __expf(-d));
    float term = si * w2[j];
#pragma unroll
    for (int m = 1; m < 64; m <<= 1) term += __shfl_xor(term, m, 64);
    __syncthreads();
    if ((j & 63) == 0) tw[j >> 6] = term;
    __syncthreads();
    if (j == 0) {
      float pre = tw[0] + tw[1];
      float learned = 1.f / (1.f + __expf(-pre));
      const float n = (float)S_ * (float)E_;
      float sum = st[b], ssq = st[4 + b];
      float var = (ssq - sum * sum / n) / (n - 1.f);
      float vn = 1.f / (1.f + __expf(-(var * 10.f - 5.f)));
      comp[b] = 0.5f * (vn + learned);
    }
    __syncthreads();
  }
  if (j == 0) {
    float mean = 0.25f * (comp[0] + comp[1] + comp[2] + comp[3]);
    float wsf = 256.f + mean * 768.f;
    int v = (int)wsf;
    v = v < 256 ? 256 : (v > S_ ? S_ : v);
    ((int*)st)[2056] = v;
  }
}

// ---------------- 128x128 bf16 MFMA GEMM, double-buffered 2-phase ----------------
// C = A[M][K] * W[N][K]^T.  EPI: 0 = QKV (RoPE + scatter), 1 = +resid -> f32 out
// 1-D grid (divisible by 8), XCD-swizzled, bn-fast logical order.
struct EpiArgs {
  u16* q; u16* k; u16* vt;
  const float* cosT; const float* sinT;
  const float* resid; float* outf;
};

template <int N, int K, int EPI, int WAVES>
__global__ __launch_bounds__(WAVES * 64) void gemm_k(const u16* __restrict__ A,
                                                     const u16* __restrict__ W,
                                                     EpiArgs ea) {
  constexpr int NBN = N / 128;
  __shared__ u16 sA[2][128 * 32];
  __shared__ u16 sB[2][128 * 32];
  const int tid = threadIdx.x;
  const int nwg = (int)gridDim.x;
  const int bid = (int)blockIdx.x;
  const int logical = (bid & 7) * (nwg >> 3) + (bid >> 3);
  const int bm = logical / NBN, bn = logical % NBN;
  const int lane = tid & 63, w = tid >> 6;
  const int g = lane >> 4, c = lane & 15;
  constexpr int MI = (WAVES == 4) ? 4 : 2;
  const int wrow = (w >> 1) * ((WAVES == 4) ? 64 : 32);
  const int wcol = (w & 1) * 64;

  const int srow = tid >> 2, sch = tid & 3;
  const u16* gA = A + (size_t)(bm * 128 + srow) * K + sch * 8;
  const u16* gB = W + (size_t)(bn * 128 + srow) * K + sch * 8;
  const int lofs = w * 1024;   // bytes within buffer

  f32x4 acc[MI][4];
  f32x4 zz = {0.f, 0.f, 0.f, 0.f};
#pragma unroll
  for (int i = 0; i < MI; ++i)
#pragma unroll
    for (int j = 0; j < 4; ++j) acc[i][j] = zz;

  auto stage = [&](int buf, int ko) {
    GLOAD16(gA + ko, (char*)sA[buf] + lofs);
    GLOAD16(gB + ko, (char*)sB[buf] + lofs);
    if constexpr (WAVES == 4) {
      GLOAD16(gA + (size_t)64 * K + ko, (char*)sA[buf] + lofs + 4096);
      GLOAD16(gB + (size_t)64 * K + ko, (char*)sB[buf] + lofs + 4096);
    }
  };

  constexpr int NIT = K / 32;
  stage(0, 0);
  __syncthreads();
  int cur = 0;
  for (int it = 0; it < NIT; ++it) {
    if (it + 1 < NIT) stage(cur ^ 1, (it + 1) * 32);
    const u16* bufA = sA[cur];
    const u16* bufB = sB[cur];
    bf16x8 af[MI], bfr[4];
#pragma unroll
    for (int mi = 0; mi < MI; ++mi)
      af[mi] = *(const bf16x8*)&bufA[(wrow + mi * 16 + c) * 32 + g * 8];
#pragma unroll
    for (int nj = 0; nj < 4; ++nj)
      bfr[nj] = *(const bf16x8*)&bufB[(wcol + nj * 16 + c) * 32 + g * 8];
#pragma unroll
    for (int mi = 0; mi < MI; ++mi)
#pragma unroll
      for (int nj = 0; nj < 4; ++nj)
        acc[mi][nj] = __builtin_amdgcn_mfma_f32_16x16x32_bf16(af[mi], bfr[nj], acc[mi][nj], 0, 0, 0);
    __syncthreads();
    cur ^= 1;
  }

#pragma unroll
  for (int mi = 0; mi < MI; ++mi) {
#pragma unroll
    for (int nj = 0; nj < 4; ++nj) {
      const int rowb = bm * 128 + wrow + mi * 16 + 4 * g;
      const int cc = bn * 128 + wcol + nj * 16 + c;
      if constexpr (EPI == 0) {
        const int which = cc >> 9;
        const int hh = (cc >> 6) & 7;
        const int d = cc & 63;
        const int bi = rowb >> 11;
        const int s = rowb & (S_ - 1);
        if (which == 2) {  // V -> transposed [bh][d][s]
          u32x2 pk;
          pk.x = pkbf(acc[mi][nj][0], acc[mi][nj][1]);
          pk.y = pkbf(acc[mi][nj][2], acc[mi][nj][3]);
          *(u32x2*)(ea.vt + (((size_t)(bi * H_ + hh) * D_ + d) * S_ + s)) = pk;
        } else {           // Q/K with interleaved RoPE
          u16* dst = (which == 0 ? ea.q : ea.k) + (((size_t)(bi * H_ + hh) * S_ + s) * D_ + d);
#pragma unroll
          for (int r = 0; r < 4; ++r) {
            float v = acc[mi][nj][r];
            float pv = __shfl_xor(v, 1, 64);
            int si = s + r;
            float cs = ea.cosT[si * 64 + d];
            float sn = ea.sinT[si * 64 + d];
            float o = v * cs + ((d & 1) ? pv : -pv) * sn;
            dst[(size_t)r * D_] = f2bf(o);
          }
        }
      } else {  // EPI 1: +resid -> f32
#pragma unroll
        for (int r = 0; r < 4; ++r) {
          size_t idx = (size_t)(rowb + r) * N + cc;
          ea.outf[idx] = acc[mi][nj][r] + ea.resid[idx];
        }
      }
    }
  }
}

// ---------------- fused gate+up GEMM with silu epilogue (8 waves, dbuf) ----------------
__global__ __launch_bounds__(512) void gemmgu_k(const u16* __restrict__ A,
                                                const u16* __restrict__ Wg,
                                                const u16* __restrict__ Wu,
                                                u16* __restrict__ outb) {
  __shared__ u16 sA[2][128 * 32];
  __shared__ u16 sG[2][128 * 32];
  __shared__ u16 sU[2][128 * 32];
  const int tid = threadIdx.x;
  const int nwg = (int)gridDim.x;          // 1152
  const int bid = (int)blockIdx.x;
  const int logical = (bid & 7) * (nwg >> 3) + (bid >> 3);
  const int bm = logical / 18, bn = logical % 18;
  const int lane = tid & 63, w = tid >> 6;
  const int g = lane >> 4, c = lane & 15;
  const int wrow = (w >> 1) * 32;
  const int wcol = (w & 1) * 64;

  const int srow = tid >> 2, sch = tid & 3;
  const u16* gA = A + (size_t)(bm * 128 + srow) * 512 + sch * 8;
  const u16* gG = Wg + (size_t)(bn * 128 + srow) * 512 + sch * 8;
  const u16* gU = Wu + (size_t)(bn * 128 + srow) * 512 + sch * 8;
  const int lofs = w * 1024;

  f32x4 accg[2][4], accu[2][4];
  f32x4 zz = {0.f, 0.f, 0.f, 0.f};
#pragma unroll
  for (int i = 0; i < 2; ++i)
#pragma unroll
    for (int j = 0; j < 4; ++j) { accg[i][j] = zz; accu[i][j] = zz; }

  auto stage = [&](int buf, int ko) {
    GLOAD16(gA + ko, (char*)sA[buf] + lofs);
    GLOAD16(gG + ko, (char*)sG[buf] + lofs);
    GLOAD16(gU + ko, (char*)sU[buf] + lofs);
  };

  stage(0, 0);
  __syncthreads();
  int cur = 0;
  for (int it = 0; it < 16; ++it) {
    if (it + 1 < 16) stage(cur ^ 1, (it + 1) * 32);
    const u16* bufA = sA[cur];
    const u16* bufG = sG[cur];
    const u16* bufU = sU[cur];
    bf16x8 af[2], bg[4], bu[4];
#pragma unroll
    for (int mi = 0; mi < 2; ++mi)
      af[mi] = *(const bf16x8*)&bufA[(wrow + mi * 16 + c) * 32 + g * 8];
#pragma unroll
    for (int nj = 0; nj < 4; ++nj) {
      bg[nj] = *(const bf16x8*)&bufG[(wcol + nj * 16 + c) * 32 + g * 8];
      bu[nj] = *(const bf16x8*)&bufU[(wcol + nj * 16 + c) * 32 + g * 8];
    }
#pragma unroll
    for (int mi = 0; mi < 2; ++mi)
#pragma unroll
      for (int nj = 0; nj < 4; ++nj) {
        accg[mi][nj] = __builtin_amdgcn_mfma_f32_16x16x32_bf16(af[mi], bg[nj], accg[mi][nj], 0, 0, 0);
        accu[mi][nj] = __builtin_amdgcn_mfma_f32_16x16x32_bf16(af[mi], bu[nj], accu[mi][nj], 0, 0, 0);
      }
    __syncthreads();
    cur ^= 1;
  }

#pragma unroll
  for (int mi = 0; mi < 2; ++mi) {
#pragma unroll
    for (int nj = 0; nj < 4; ++nj) {
      const int rowb = bm * 128 + wrow + mi * 16 + 4 * g;
      const int cc = bn * 128 + wcol + nj * 16 + c;
#pragma unroll
      for (int r = 0; r < 4; ++r) {
        float gv = accg[mi][nj][r];
        float uv = accu[mi][nj][r];
        float sil = gv / (1.f + __expf(-gv));
        outb[(size_t)(rowb + r) * 2304 + cc] = f2bf(sil * uv);
      }
    }
  }
}

// ---------------- sliding-window flash attention, KBLK=64, V-overlap ----------------
__global__ __launch_bounds__(256) void attn_k(const u16* __restrict__ Qb,
                                              const u16* __restrict__ Kb,
                                              const u16* __restrict__ Vt,
                                              u16* __restrict__ ao,
                                              const int* __restrict__ wsp) {
  const int bh = blockIdx.x;
  const int b = bh >> 3, h = bh & 7;
  const int qt = blockIdx.y;
  const int tid = threadIdx.x;
  const int w = tid >> 6, lane = tid & 63;
  const int g = lane >> 4, c = lane & 15;
  const int ws = *wsp;
  const int qw = qt * 64 + w * 16;
  const u16* Qh = Qb + (size_t)bh * S_ * D_;
  const u16* Kh = Kb + (size_t)bh * S_ * D_;
  const u16* Vh = Vt + (size_t)bh * D_ * S_;

  bf16x8 qf0 = *(const bf16x8*)(Qh + (qw + c) * D_ + g * 8);
  bf16x8 qf1 = *(const bf16x8*)(Qh + (qw + c) * D_ + 32 + g * 8);

  const float SCL = 0.125f * 1.44269504089f;   // d^-0.5 * log2(e)
  float m2 = -3e38f, lsum = 0.f;
  f32x4 O[4];
  f32x4 zz = {0.f, 0.f, 0.f, 0.f};
#pragma unroll
  for (int i = 0; i < 4; ++i) O[i] = zz;

  int lo = qw - ws + 1;
  if (lo < 0) lo = 0;
  const int q = qw + c;
  for (int kb = lo & ~63; kb <= qw + 15; kb += 64) {
    // K fragments
    bf16x8 kf[4][2];
#pragma unroll
    for (int t = 0; t < 4; ++t) {
      const u16* kp = Kh + (kb + 16 * t + c) * D_;
      kf[t][0] = *(const bf16x8*)(kp + g * 8);
      kf[t][1] = *(const bf16x8*)(kp + 32 + g * 8);
    }
    f32x4 st4[4];
    __builtin_amdgcn_s_setprio(1);
#pragma unroll
    for (int t = 0; t < 4; ++t) {
      f32x4 s = zz;
      s = __builtin_amdgcn_mfma_f32_16x16x32_bf16(kf[t][0], qf0, s, 0, 0, 0);
      s = __builtin_amdgcn_mfma_f32_16x16x32_bf16(kf[t][1], qf1, s, 0, 0, 0);
      st4[t] = s;
    }
    __builtin_amdgcn_s_setprio(0);
    // issue V loads now; latency hides under the softmax chain
    bf16x8 vf[4][2];
#pragma unroll
    for (int dt = 0; dt < 4; ++dt) {
      const u16* vp = Vh + (size_t)(dt * 16 + c) * S_ + kb;
      vf[dt][0] = *(const bf16x8*)(vp + g * 8);
      vf[dt][1] = *(const bf16x8*)(vp + 32 + g * 8);
    }
    // mask (skipped for interior blocks) + block max
    const bool interior = (kb + 63 <= qw) && (kb >= qw + 16 - ws);
    float p[4][4];
    float bm = -3e38f;
    if (interior) {
#pragma unroll
      for (int t = 0; t < 4; ++t)
#pragma unroll
        for (int r = 0; r < 4; ++r) {
          p[t][r] = st4[t][r] * SCL;
          bm = fmaxf(bm, p[t][r]);
        }
    } else {
#pragma unroll
      for (int t = 0; t < 4; ++t)
#pragma unroll
        for (int r = 0; r < 4; ++r) {
          int ki = kb + 16 * t + 4 * g + r;
          float v = st4[t][r] * SCL;
          bool ok = (q >= ki) && (q - ki) < ws;
          p[t][r] = ok ? v : -__builtin_inff();
          bm = fmaxf(bm, p[t][r]);
        }
    }
    bm = fmaxf(bm, __shfl_xor(bm, 16, 64));
    bm = fmaxf(bm, __shfl_xor(bm, 32, 64));
    if (!__all(bm - m2 <= 8.f)) {          // T13 defer-max
      float mnew = fmaxf(m2, bm);
      float al = exp2f(m2 - mnew);
      lsum *= al;
#pragma unroll
      for (int i = 0; i < 4; ++i) O[i] *= al;
      m2 = mnew;
    }
    float psum = 0.f;
#pragma unroll
    for (int t = 0; t < 4; ++t)
#pragma unroll
      for (int r = 0; r < 4; ++r) {
        p[t][r] = exp2f(p[t][r] - m2);     // masked -> 0
        psum += p[t][r];
      }
    psum += __shfl_xor(psum, 16, 64);
    psum += __shfl_xor(psum, 32, 64);
    lsum += psum;

    // pack P to bf16 pairs, redistribute to PV B-frag layout
    u32 pp[4][2];
#pragma unroll
    for (int t = 0; t < 4; ++t) {
      pp[t][0] = pkbf(p[t][0], p[t][1]);
      pp[t][1] = pkbf(p[t][2], p[t][3]);
    }
    const int lA = (g & 1) * 32 + c;
    const int lB = lA + 16;
    const int hi = g >> 1;
    union { bf16x8 v; u32 u[4]; } pf0, pf1;
#pragma unroll
    for (int wi = 0; wi < 2; ++wi) {
      u32 a0 = (u32)__shfl((int)pp[0][wi], lA, 64);
      u32 a1 = (u32)__shfl((int)pp[1][wi], lA, 64);
      u32 a2 = (u32)__shfl((int)pp[2][wi], lA, 64);
      u32 a3 = (u32)__shfl((int)pp[3][wi], lA, 64);
      u32 b0 = (u32)__shfl((int)pp[0][wi], lB, 64);
      u32 b1 = (u32)__shfl((int)pp[1][wi], lB, 64);
      u32 b2 = (u32)__shfl((int)pp[2][wi], lB, 64);
      u32 b3 = (u32)__shfl((int)pp[3][wi], lB, 64);
      pf0.u[wi]     = hi ? a1 : a0;
      pf0.u[2 + wi] = hi ? b1 : b0;
      pf1.u[wi]     = hi ? a3 : a2;
      pf1.u[2 + wi] = hi ? b3 : b2;
    }
    // PV: O^T[d][q] += V^T[d][k] P[k][q]
    __builtin_amdgcn_s_setprio(1);
#pragma unroll
    for (int dt = 0; dt < 4; ++dt) {
      O[dt] = __builtin_amdgcn_mfma_f32_16x16x32_bf16(vf[dt][0], pf0.v, O[dt], 0, 0, 0);
      O[dt] = __builtin_amdgcn_mfma_f32_16x16x32_bf16(vf[dt][1], pf1.v, O[dt], 0, 0, 0);
    }
    __builtin_amdgcn_s_setprio(0);
  }

  float inv = 1.f / lsum;
  __shared__ u16 ob[4][16][80];   // padded rows
#pragma unroll
  for (int dt = 0; dt < 4; ++dt)
#pragma unroll
    for (int r = 0; r < 4; ++r)
      ob[w][c][dt * 16 + 4 * g + r] = f2bf(O[dt][r] * inv);
  __syncthreads();
#pragma unroll
  for (int it = 0; it < 2; ++it) {
    int linear = tid + it * 256;
    int qrow = linear >> 3, ch = linear & 7;
    u32x4 v = *(const u32x4*)&ob[qrow >> 4][qrow & 15][ch * 8];
    *(u32x4*)(ao + ((size_t)(b * S_ + qt * 64 + qrow)) * E_ + h * D_ + ch * 8) = v;
  }
}

// ---------------- launcher ----------------
extern "C" void kernel_launch(void* const* d_in, const int* in_sizes, int n_in,
                              void* d_out, int out_size, void* d_ws, size_t ws_size,
                              hipStream_t stream) {
  const float* x      = (const float*)d_in[0];
  const float* rms1_w = (const float*)d_in[1];
  const float* rms2_w = (const float*)d_in[2];
  const float* qkv_w  = (const float*)d_in[3];
  const float* out_w  = (const float*)d_in[4];
  const float* cs_w1  = (const float*)d_in[5];
  const float* cs_w2  = (const float*)d_in[6];
  const float* gate_w = (const float*)d_in[7];
  const float* up_w   = (const float*)d_in[8];
  const float* down_w = (const float*)d_in[9];

  char* ws = (char*)d_ws;
  constexpr size_t o_wqkv = 0;                       // 1536*512*2
  constexpr size_t o_wout = 1572864;                 // 512*512*2
  constexpr size_t o_wgate = 2097152;                // 2304*512*2
  constexpr size_t o_wup = 4456448;
  constexpr size_t o_wdown = 6815744;                // 512*2304*2
  constexpr size_t o_h = 9175040;                    // 8192*512*2  (alias: attnout)
  constexpr size_t o_stats = 17563648;               // 16KB
  constexpr size_t o_cos = 17580032;                 // 2048*64*4
  constexpr size_t o_sin = 18104320;
  constexpr size_t o_Q = 18628608;                   // 8192*512*2  (alias: h2)
  constexpr size_t o_K = 27017216;
  constexpr size_t o_Vt = 35405824;
  constexpr size_t o_x2 = 43794432;                  // 8192*512*4
  constexpr size_t o_gate = 60571648;                // 8192*2304*2

  u16* wqkv = (u16*)(ws + o_wqkv);
  u16* wout = (u16*)(ws + o_wout);
  u16* wgate = (u16*)(ws + o_wgate);
  u16* wup = (u16*)(ws + o_wup);
  u16* wdown = (u16*)(ws + o_wdown);
  u16* h = (u16*)(ws + o_h);
  float* stats = (float*)(ws + o_stats);
  float* cosT = (float*)(ws + o_cos);
  float* sinT = (float*)(ws + o_sin);
  u16* Qb = (u16*)(ws + o_Q);
  u16* Kb = (u16*)(ws + o_K);
  u16* Vt = (u16*)(ws + o_Vt);
  float* x2 = (float*)(ws + o_x2);
  u16* gateb = (u16*)(ws + o_gate);
  u16* attno = h;
  u16* h2 = Qb;

  hipMemsetAsync(stats, 0, 16384, stream);
  cvt_k<<<768, 256, 0, stream>>>(qkv_w, wqkv, 1536 * 512);
  cvt_k<<<256, 256, 0, stream>>>(out_w, wout, 512 * 512);
  cvt_k<<<1152, 256, 0, stream>>>(gate_w, wgate, 2304 * 512);
  cvt_k<<<1152, 256, 0, stream>>>(up_w, wup, 2304 * 512);
  cvt_k<<<1152, 256, 0, stream>>>(down_w, wdown, 512 * 2304);
  ropetab_k<<<512, 256, 0, stream>>>(cosT, sinT);

  rmsnorm_k<<<8192, 256, 0, stream>>>(x, rms1_w, h);
  colsum_k<<<32, 256, 0, stream>>>(h, stats);
  wscalc_k<<<1, 128, 0, stream>>>(stats, cs_w1, cs_w2);

  EpiArgs ea{};
  ea.q = Qb; ea.k = Kb; ea.vt = Vt; ea.cosT = cosT; ea.sinT = sinT;
  gemm_k<1536, 512, 0, 4><<<768, 256, 0, stream>>>(h, wqkv, ea);

  attn_k<<<dim3(32, 32), 256, 0, stream>>>(Qb, Kb, Vt, attno, (const int*)(stats + 2056));

  EpiArgs e2{};
  e2.resid = x; e2.outf = x2;
  gemm_k<512, 512, 1, 8><<<256, 512, 0, stream>>>(attno, wout, e2);

  rmsnorm_k<<<8192, 256, 0, stream>>>(x2, rms2_w, h2);

  gemmgu_k<<<1152, 512, 0, stream>>>(h2, wgate, wup, gateb);

  EpiArgs e5{};
  e5.resid = x2; e5.outf = (float*)d_out;
  gemm_k<512, 2304, 1, 8><<<256, 512, 0, stream>>>(gateb, wdown, e5);

  (void)in_sizes; (void)n_in; (void)out_size; (void)ws_size;
}

// Round 7
// 396.953 us; speedup vs baseline: 1.0274x; 1.0274x over previous
//
#include <hip/hip_runtime.h>

typedef unsigned short u16;
typedef unsigned int   u32;
typedef __attribute__((ext_vector_type(4))) float  f32x4;
typedef __attribute__((ext_vector_type(8))) __bf16 bf16x8;
typedef __attribute__((ext_vector_type(4))) u32    u32x4;
typedef __attribute__((ext_vector_type(2))) u32    u32x2;

#define B_ 4
#define S_ 2048
#define E_ 512
#define H_ 8
#define D_ 64

__device__ __forceinline__ u16 f2bf(float f) {
  union { float f; u32 u; } a; a.f = f;
  u32 r = a.u + 0x7FFFu + ((a.u >> 16) & 1u);   // RNE
  return (u16)(r >> 16);
}
__device__ __forceinline__ float bf2f(u16 u) {
  union { u32 u; float f; } a; a.u = (u32)u << 16;
  return a.f;
}
__device__ __forceinline__ u32 pkbf(float lo, float hi) {  // bf16(lo) | bf16(hi)<<16
  u32 r;
  asm("v_cvt_pk_bf16_f32 %0, %1, %2" : "=v"(r) : "v"(lo), "v"(hi));
  return r;
}

// async global->LDS, 16B per lane; lds ptr wave-uniform (HW adds lane*16)
#define GLOAD16(gp, lp) __builtin_amdgcn_global_load_lds( \
    (const __attribute__((address_space(1))) void*)(gp),  \
    (__attribute__((address_space(3))) void*)(lp), 16, 0, 0)

#define BARRIER() asm volatile("s_barrier" ::: "memory")

// ---------------- weight fp32 -> bf16 convert ----------------
__global__ __launch_bounds__(256) void cvt_k(const float* __restrict__ s,
                                             u16* __restrict__ d, int n) {
  int i = (blockIdx.x * 256 + threadIdx.x) * 4;
  if (i >= n) return;
  f32x4 v = *(const f32x4*)(s + i);
  u32x2 o;
  o.x = pkbf(v[0], v[1]);
  o.y = pkbf(v[2], v[3]);
  *(u32x2*)(d + i) = o;
}

// ---------------- RoPE cos/sin table ----------------
__global__ __launch_bounds__(256) void ropetab_k(float* __restrict__ ct,
                                                 float* __restrict__ st) {
  int idx = blockIdx.x * 256 + threadIdx.x;   // S_*64 total
  int s = idx >> 6, j = idx & 63;
  float f = powf(10000.f, -(float)(j & 31) * (1.f / 32.f));
  float ang = (float)s * f;
  ct[idx] = cosf(ang);
  st[idx] = sinf(ang);
}

// ---------------- RMSNorm (row of 512), fp32 in -> bf16 out ----------------
__global__ __launch_bounds__(256) void rmsnorm_k(const float* __restrict__ x,
                                                 const float* __restrict__ wv,
                                                 u16* __restrict__ o) {
  const int row = blockIdx.x;
  const int t = threadIdx.x;
  const float* xr = x + (size_t)row * E_;
  float v0 = xr[t], v1 = xr[t + 256];
  float ss = v0 * v0 + v1 * v1;
#pragma unroll
  for (int m = 1; m < 64; m <<= 1) ss += __shfl_xor(ss, m, 64);
  __shared__ float red[4];
  if ((t & 63) == 0) red[t >> 6] = ss;
  __syncthreads();
  float tot = red[0] + red[1] + red[2] + red[3];
  float rms = 1.f / sqrtf(tot * (1.f / (float)E_) + 1e-6f);
  o[(size_t)row * E_ + t]       = f2bf(v0 * rms * wv[t]);
  o[(size_t)row * E_ + t + 256] = f2bf(v1 * rms * wv[t + 256]);
}

// ------------- column sums (xm) + batch sum/sumsq of h -------------
__global__ __launch_bounds__(256) void colsum_k(const u16* __restrict__ h,
                                                float* __restrict__ st) {
  const int b = blockIdx.x >> 3, ck = blockIdx.x & 7;
  const u16* hb = h + ((size_t)b * S_ + ck * 256) * E_;
  const int t = threadIdx.x;
  float a0 = 0, a1 = 0, s = 0, sq = 0;
  for (int r = 0; r < 256; ++r) {
    float v0 = bf2f(hb[(size_t)r * E_ + t]);
    float v1 = bf2f(hb[(size_t)r * E_ + t + 256]);
    a0 += v0; a1 += v1;
    s += v0 + v1; sq += v0 * v0 + v1 * v1;
  }
  atomicAdd(&st[8 + b * E_ + t], a0);
  atomicAdd(&st[8 + b * E_ + t + 256], a1);
#pragma unroll
  for (int m = 1; m < 64; m <<= 1) { s += __shfl_xor(s, m, 64); sq += __shfl_xor(sq, m, 64); }
  if ((t & 63) == 0) { atomicAdd(&st[b], s); atomicAdd(&st[4 + b], sq); }
}

// ------------- complexity -> window size scalar -------------
__global__ __launch_bounds__(128) void wscalc_k(float* __restrict__ st,
                                                const float* __restrict__ w1,
                                                const float* __restrict__ w2) {
  const int j = threadIdx.x;
  __shared__ float comp[4];
  __shared__ float tw[2];
  float dot[4] = {0.f, 0.f, 0.f, 0.f};
  const float* w1r = w1 + (size_t)j * E_;
  for (int e = 0; e < E_; ++e) {
    float wv = w1r[e];
    dot[0] += st[8 + 0 * E_ + e] * wv;
    dot[1] += st[8 + 1 * E_ + e] * wv;
    dot[2] += st[8 + 2 * E_ + e] * wv;
    dot[3] += st[8 + 3 * E_ + e] * wv;
  }
  for (int b = 0; b < 4; ++b) {
    float d = dot[b] * (1.f / (float)S_);
    float si = d / (1.f + __expf(-d));
    float term = si * w2[j];
#pragma unroll
    for (int m = 1; m < 64; m <<= 1) term += __shfl_xor(term, m, 64);
    __syncthreads();
    if ((j & 63) == 0) tw[j >> 6] = term;
    __syncthreads();
    if (j == 0) {
      float pre = tw[0] + tw[1];
      float learned = 1.f / (1.f + __expf(-pre));
      const float n = (float)S_ * (float)E_;
      float sum = st[b], ssq = st[4 + b];
      float var = (ssq - sum * sum / n) / (n - 1.f);
      float vn = 1.f / (1.f + __expf(-(var * 10.f - 5.f)));
      comp[b] = 0.5f * (vn + learned);
    }
    __syncthreads();
  }
  if (j == 0) {
    float mean = 0.25f * (comp[0] + comp[1] + comp[2] + comp[3]);
    float wsf = 256.f + mean * 768.f;
    int v = (int)wsf;
    v = v < 256 ? 256 : (v > S_ ? S_ : v);
    ((int*)st)[2056] = v;
  }
}

// ---------------- 128x128 bf16 GEMM: dbuf + counted vmcnt + swizzled LDS ----------------
// C = A[M][K] * W[N][K]^T.  EPI: 0 = QKV (RoPE + scatter), 1 = +resid -> f32 out
// LDS[r][j] = global[r][j ^ ((r>>1)&3)]  (16B chunks; involution on both sides)
struct EpiArgs {
  u16* q; u16* k; u16* vt;
  const float* cosT; const float* sinT;
  const float* resid; float* outf;
};

template <int N, int K, int EPI, int WAVES>
__global__ __launch_bounds__(WAVES * 64) void gemm_k(const u16* __restrict__ A,
                                                     const u16* __restrict__ W,
                                                     EpiArgs ea) {
  constexpr int NBN = N / 128;
  __shared__ u16 sA[2][128 * 32];
  __shared__ u16 sB[2][128 * 32];
  const int tid = threadIdx.x;
  const int nwg = (int)gridDim.x;
  const int bid = (int)blockIdx.x;
  const int logical = (bid & 7) * (nwg >> 3) + (bid >> 3);
  const int bm = logical / NBN, bn = logical % NBN;
  const int lane = tid & 63, w = tid >> 6;
  const int g = lane >> 4, c = lane & 15;
  constexpr int MI = (WAVES == 4) ? 4 : 2;
  const int wrow = (w >> 1) * ((WAVES == 4) ? 64 : 32);
  const int wcol = (w & 1) * 64;

  // staging: lane covers LDS row sr0 (and sr0+64 for 4-wave), chunk lane&3 (linear dest);
  // source chunk pre-swizzled so that read-side XOR finds the right data
  const int sr0 = w * 16 + (lane >> 2);
  const int ch0 = (lane & 3) ^ ((sr0 >> 1) & 3);   // (sr0+64)>>1 & 3 is identical
  const u16* gA = A + (size_t)(bm * 128 + sr0) * K + ch0 * 8;
  const u16* gB = W + (size_t)(bn * 128 + sr0) * K + ch0 * 8;
  const int lofs = w * 1024;

  f32x4 acc[MI][4];
  f32x4 zz = {0.f, 0.f, 0.f, 0.f};
#pragma unroll
  for (int i = 0; i < MI; ++i)
#pragma unroll
    for (int j = 0; j < 4; ++j) acc[i][j] = zz;

  auto stage = [&](int buf, int ko) {
    GLOAD16(gA + ko, (char*)sA[buf] + lofs);
    GLOAD16(gB + ko, (char*)sB[buf] + lofs);
    if constexpr (WAVES == 4) {
      GLOAD16(gA + (size_t)64 * K + ko, (char*)sA[buf] + lofs + 4096);
      GLOAD16(gB + (size_t)64 * K + ko, (char*)sB[buf] + lofs + 4096);
    }
  };

  constexpr int NIT = K / 32;
  stage(0, 0);
  int cur = 0;
  for (int it = 0; it < NIT; ++it) {
    if (it + 1 < NIT) {
      stage(cur ^ 1, (it + 1) * 32);
      if constexpr (WAVES == 4) asm volatile("s_waitcnt vmcnt(4)" ::: "memory");
      else                      asm volatile("s_waitcnt vmcnt(2)" ::: "memory");
    } else {
      asm volatile("s_waitcnt vmcnt(0)" ::: "memory");
    }
    BARRIER();
    const u16* bufA = sA[cur];
    const u16* bufB = sB[cur];
    bf16x8 af[MI], bfr[4];
#pragma unroll
    for (int mi = 0; mi < MI; ++mi) {
      int ar = wrow + mi * 16 + c;
      af[mi] = *(const bf16x8*)&bufA[ar * 32 + ((g ^ ((ar >> 1) & 3)) * 8)];
    }
#pragma unroll
    for (int nj = 0; nj < 4; ++nj) {
      int br = wcol + nj * 16 + c;
      bfr[nj] = *(const bf16x8*)&bufB[br * 32 + ((g ^ ((br >> 1) & 3)) * 8)];
    }
#pragma unroll
    for (int mi = 0; mi < MI; ++mi)
#pragma unroll
      for (int nj = 0; nj < 4; ++nj)
        acc[mi][nj] = __builtin_amdgcn_mfma_f32_16x16x32_bf16(af[mi], bfr[nj], acc[mi][nj], 0, 0, 0);
    BARRIER();
    cur ^= 1;
  }

#pragma unroll
  for (int mi = 0; mi < MI; ++mi) {
#pragma unroll
    for (int nj = 0; nj < 4; ++nj) {
      const int rowb = bm * 128 + wrow + mi * 16 + 4 * g;
      const int cc = bn * 128 + wcol + nj * 16 + c;
      if constexpr (EPI == 0) {
        const int which = cc >> 9;
        const int hh = (cc >> 6) & 7;
        const int d = cc & 63;
        const int bi = rowb >> 11;
        const int s = rowb & (S_ - 1);
        if (which == 2) {  // V -> transposed [bh][d][s]
          u32x2 pk;
          pk.x = pkbf(acc[mi][nj][0], acc[mi][nj][1]);
          pk.y = pkbf(acc[mi][nj][2], acc[mi][nj][3]);
          *(u32x2*)(ea.vt + (((size_t)(bi * H_ + hh) * D_ + d) * S_ + s)) = pk;
        } else {           // Q/K with interleaved RoPE
          u16* dst = (which == 0 ? ea.q : ea.k) + (((size_t)(bi * H_ + hh) * S_ + s) * D_ + d);
#pragma unroll
          for (int r = 0; r < 4; ++r) {
            float v = acc[mi][nj][r];
            float pv = __shfl_xor(v, 1, 64);
            int si = s + r;
            float cs = ea.cosT[si * 64 + d];
            float sn = ea.sinT[si * 64 + d];
            float o = v * cs + ((d & 1) ? pv : -pv) * sn;
            dst[(size_t)r * D_] = f2bf(o);
          }
        }
      } else {  // EPI 1: +resid -> f32
#pragma unroll
        for (int r = 0; r < 4; ++r) {
          size_t idx = (size_t)(rowb + r) * N + cc;
          ea.outf[idx] = acc[mi][nj][r] + ea.resid[idx];
        }
      }
    }
  }
}

// ---------------- fused gate+up GEMM with silu epilogue (8 waves, dbuf, counted vmcnt) ----------------
__global__ __launch_bounds__(512) void gemmgu_k(const u16* __restrict__ A,
                                                const u16* __restrict__ Wg,
                                                const u16* __restrict__ Wu,
                                                u16* __restrict__ outb) {
  __shared__ u16 sA[2][128 * 32];
  __shared__ u16 sG[2][128 * 32];
  __shared__ u16 sU[2][128 * 32];
  const int tid = threadIdx.x;
  const int nwg = (int)gridDim.x;          // 1152
  const int bid = (int)blockIdx.x;
  const int logical = (bid & 7) * (nwg >> 3) + (bid >> 3);
  const int bm = logical / 18, bn = logical % 18;
  const int lane = tid & 63, w = tid >> 6;
  const int g = lane >> 4, c = lane & 15;
  const int wrow = (w >> 1) * 32;
  const int wcol = (w & 1) * 64;

  const int sr0 = w * 16 + (lane >> 2);
  const int ch0 = (lane & 3) ^ ((sr0 >> 1) & 3);
  const u16* gA = A + (size_t)(bm * 128 + sr0) * 512 + ch0 * 8;
  const u16* gG = Wg + (size_t)(bn * 128 + sr0) * 512 + ch0 * 8;
  const u16* gU = Wu + (size_t)(bn * 128 + sr0) * 512 + ch0 * 8;
  const int lofs = w * 1024;

  f32x4 accg[2][4], accu[2][4];
  f32x4 zz = {0.f, 0.f, 0.f, 0.f};
#pragma unroll
  for (int i = 0; i < 2; ++i)
#pragma unroll
    for (int j = 0; j < 4; ++j) { accg[i][j] = zz; accu[i][j] = zz; }

  auto stage = [&](int buf, int ko) {
    GLOAD16(gA + ko, (char*)sA[buf] + lofs);
    GLOAD16(gG + ko, (char*)sG[buf] + lofs);
    GLOAD16(gU + ko, (char*)sU[buf] + lofs);
  };

  stage(0, 0);
  int cur = 0;
  for (int it = 0; it < 16; ++it) {
    if (it + 1 < 16) {
      stage(cur ^ 1, (it + 1) * 32);
      asm volatile("s_waitcnt vmcnt(3)" ::: "memory");
    } else {
      asm volatile("s_waitcnt vmcnt(0)" ::: "memory");
    }
    BARRIER();
    const u16* bufA = sA[cur];
    const u16* bufG = sG[cur];
    const u16* bufU = sU[cur];
    bf16x8 af[2], bg[4], bu[4];
#pragma unroll
    for (int mi = 0; mi < 2; ++mi) {
      int ar = wrow + mi * 16 + c;
      af[mi] = *(const bf16x8*)&bufA[ar * 32 + ((g ^ ((ar >> 1) & 3)) * 8)];
    }
#pragma unroll
    for (int nj = 0; nj < 4; ++nj) {
      int br = wcol + nj * 16 + c;
      int sw = (g ^ ((br >> 1) & 3)) * 8;
      bg[nj] = *(const bf16x8*)&bufG[br * 32 + sw];
      bu[nj] = *(const bf16x8*)&bufU[br * 32 + sw];
    }
#pragma unroll
    for (int mi = 0; mi < 2; ++mi)
#pragma unroll
      for (int nj = 0; nj < 4; ++nj) {
        accg[mi][nj] = __builtin_amdgcn_mfma_f32_16x16x32_bf16(af[mi], bg[nj], accg[mi][nj], 0, 0, 0);
        accu[mi][nj] = __builtin_amdgcn_mfma_f32_16x16x32_bf16(af[mi], bu[nj], accu[mi][nj], 0, 0, 0);
      }
    BARRIER();
    cur ^= 1;
  }

#pragma unroll
  for (int mi = 0; mi < 2; ++mi) {
#pragma unroll
    for (int nj = 0; nj < 4; ++nj) {
      const int rowb = bm * 128 + wrow + mi * 16 + 4 * g;
      const int cc = bn * 128 + wcol + nj * 16 + c;
#pragma unroll
      for (int r = 0; r < 4; ++r) {
        float gv = accg[mi][nj][r];
        float uv = accu[mi][nj][r];
        float sil = gv / (1.f + __expf(-gv));
        outb[(size_t)(rowb + r) * 2304 + cc] = f2bf(sil * uv);
      }
    }
  }
}

// ---------------- sliding-window flash attention ----------------
// 2048 blocks x 128 threads (2 waves, 16 queries each), longest-window-first order.
__global__ __launch_bounds__(128) void attn_k(const u16* __restrict__ Qb,
                                              const u16* __restrict__ Kb,
                                              const u16* __restrict__ Vt,
                                              u16* __restrict__ ao,
                                              const int* __restrict__ wsp) {
  const int bid = (int)blockIdx.x;
  const int qh = 63 - (bid >> 5);          // descending work
  const int bh = bid & 31;
  const int b = bh >> 3, h = bh & 7;
  const int tid = threadIdx.x;
  const int w = tid >> 6, lane = tid & 63;
  const int g = lane >> 4, c = lane & 15;
  const int ws = *wsp;
  const int qw = qh * 32 + w * 16;
  const u16* Qh = Qb + (size_t)bh * S_ * D_;
  const u16* Kh = Kb + (size_t)bh * S_ * D_;
  const u16* Vh = Vt + (size_t)bh * D_ * S_;

  bf16x8 qf0 = *(const bf16x8*)(Qh + (qw + c) * D_ + g * 8);
  bf16x8 qf1 = *(const bf16x8*)(Qh + (qw + c) * D_ + 32 + g * 8);

  const float SCL = 0.125f * 1.44269504089f;   // d^-0.5 * log2(e)
  float m2 = -3e38f, lsum = 0.f;
  f32x4 O[4];
  f32x4 zz = {0.f, 0.f, 0.f, 0.f};
#pragma unroll
  for (int i = 0; i < 4; ++i) O[i] = zz;

  int lo = qw - ws + 1;
  if (lo < 0) lo = 0;
  const int q = qw + c;
  for (int kb = lo & ~63; kb <= qw + 15; kb += 64) {
    bf16x8 kf[4][2];
#pragma unroll
    for (int t = 0; t < 4; ++t) {
      const u16* kp = Kh + (kb + 16 * t + c) * D_;
      kf[t][0] = *(const bf16x8*)(kp + g * 8);
      kf[t][1] = *(const bf16x8*)(kp + 32 + g * 8);
    }
    f32x4 st4[4];
    __builtin_amdgcn_s_setprio(1);
#pragma unroll
    for (int t = 0; t < 4; ++t) {
      f32x4 s = zz;
      s = __builtin_amdgcn_mfma_f32_16x16x32_bf16(kf[t][0], qf0, s, 0, 0, 0);
      s = __builtin_amdgcn_mfma_f32_16x16x32_bf16(kf[t][1], qf1, s, 0, 0, 0);
      st4[t] = s;
    }
    __builtin_amdgcn_s_setprio(0);
    bf16x8 vf[4][2];
#pragma unroll
    for (int dt = 0; dt < 4; ++dt) {
      const u16* vp = Vh + (size_t)(dt * 16 + c) * S_ + kb;
      vf[dt][0] = *(const bf16x8*)(vp + g * 8);
      vf[dt][1] = *(const bf16x8*)(vp + 32 + g * 8);
    }
    const bool interior = (kb + 63 <= qw) && (kb >= qw + 16 - ws);
    float p[4][4];
    float bm = -3e38f;
    if (interior) {
#pragma unroll
      for (int t = 0; t < 4; ++t)
#pragma unroll
        for (int r = 0; r < 4; ++r) {
          p[t][r] = st4[t][r] * SCL;
          bm = fmaxf(bm, p[t][r]);
        }
    } else {
#pragma unroll
      for (int t = 0; t < 4; ++t)
#pragma unroll
        for (int r = 0; r < 4; ++r) {
          int ki = kb + 16 * t + 4 * g + r;
          float v = st4[t][r] * SCL;
          bool ok = (q >= ki) && (q - ki) < ws;
          p[t][r] = ok ? v : -__builtin_inff();
          bm = fmaxf(bm, p[t][r]);
        }
    }
    bm = fmaxf(bm, __shfl_xor(bm, 16, 64));
    bm = fmaxf(bm, __shfl_xor(bm, 32, 64));
    if (!__all(bm - m2 <= 8.f)) {          // T13 defer-max
      float mnew = fmaxf(m2, bm);
      float al = exp2f(m2 - mnew);
      lsum *= al;
#pragma unroll
      for (int i = 0; i < 4; ++i) O[i] *= al;
      m2 = mnew;
    }
    float psum = 0.f;
#pragma unroll
    for (int t = 0; t < 4; ++t)
#pragma unroll
      for (int r = 0; r < 4; ++r) {
        p[t][r] = exp2f(p[t][r] - m2);     // masked -> 0
        psum += p[t][r];
      }
    psum += __shfl_xor(psum, 16, 64);
    psum += __shfl_xor(psum, 32, 64);
    lsum += psum;

    u32 pp[4][2];
#pragma unroll
    for (int t = 0; t < 4; ++t) {
      pp[t][0] = pkbf(p[t][0], p[t][1]);
      pp[t][1] = pkbf(p[t][2], p[t][3]);
    }
    const int lA = (g & 1) * 32 + c;
    const int lB = lA + 16;
    const int hi = g >> 1;
    union { bf16x8 v; u32 u[4]; } pf0, pf1;
#pragma unroll
    for (int wi = 0; wi < 2; ++wi) {
      u32 a0 = (u32)__shfl((int)pp[0][wi], lA, 64);
      u32 a1 = (u32)__shfl((int)pp[1][wi], lA, 64);
      u32 a2 = (u32)__shfl((int)pp[2][wi], lA, 64);
      u32 a3 = (u32)__shfl((int)pp[3][wi], lA, 64);
      u32 b0 = (u32)__shfl((int)pp[0][wi], lB, 64);
      u32 b1 = (u32)__shfl((int)pp[1][wi], lB, 64);
      u32 b2 = (u32)__shfl((int)pp[2][wi], lB, 64);
      u32 b3 = (u32)__shfl((int)pp[3][wi], lB, 64);
      pf0.u[wi]     = hi ? a1 : a0;
      pf0.u[2 + wi] = hi ? b1 : b0;
      pf1.u[wi]     = hi ? a3 : a2;
      pf1.u[2 + wi] = hi ? b3 : b2;
    }
    __builtin_amdgcn_s_setprio(1);
#pragma unroll
    for (int dt = 0; dt < 4; ++dt) {
      O[dt] = __builtin_amdgcn_mfma_f32_16x16x32_bf16(vf[dt][0], pf0.v, O[dt], 0, 0, 0);
      O[dt] = __builtin_amdgcn_mfma_f32_16x16x32_bf16(vf[dt][1], pf1.v, O[dt], 0, 0, 0);
    }
    __builtin_amdgcn_s_setprio(0);
  }

  float inv = 1.f / lsum;
  __shared__ u16 ob[2][16][80];
#pragma unroll
  for (int dt = 0; dt < 4; ++dt)
#pragma unroll
    for (int r = 0; r < 4; ++r)
      ob[w][c][dt * 16 + 4 * g + r] = f2bf(O[dt][r] * inv);
  __syncthreads();
#pragma unroll
  for (int it = 0; it < 2; ++it) {
    int linear = tid + it * 128;
    int qrow = linear >> 3, ch = linear & 7;
    u32x4 v = *(const u32x4*)&ob[qrow >> 4][qrow & 15][ch * 8];
    *(u32x4*)(ao + ((size_t)(b * S_ + qh * 32 + qrow)) * E_ + h * D_ + ch * 8) = v;
  }
}

// ---------------- launcher ----------------
extern "C" void kernel_launch(void* const* d_in, const int* in_sizes, int n_in,
                              void* d_out, int out_size, void* d_ws, size_t ws_size,
                              hipStream_t stream) {
  const float* x      = (const float*)d_in[0];
  const float* rms1_w = (const float*)d_in[1];
  const float* rms2_w = (const float*)d_in[2];
  const float* qkv_w  = (const float*)d_in[3];
  const float* out_w  = (const float*)d_in[4];
  const float* cs_w1  = (const float*)d_in[5];
  const float* cs_w2  = (const float*)d_in[6];
  const float* gate_w = (const float*)d_in[7];
  const float* up_w   = (const float*)d_in[8];
  const float* down_w = (const float*)d_in[9];

  char* ws = (char*)d_ws;
  constexpr size_t o_wqkv = 0;                       // 1536*512*2
  constexpr size_t o_wout = 1572864;                 // 512*512*2
  constexpr size_t o_wgate = 2097152;                // 2304*512*2
  constexpr size_t o_wup = 4456448;
  constexpr size_t o_wdown = 6815744;                // 512*2304*2
  constexpr size_t o_h = 9175040;                    // 8192*512*2  (alias: attnout)
  constexpr size_t o_stats = 17563648;               // 16KB
  constexpr size_t o_cos = 17580032;                 // 2048*64*4
  constexpr size_t o_sin = 18104320;
  constexpr size_t o_Q = 18628608;                   // 8192*512*2  (alias: h2)
  constexpr size_t o_K = 27017216;
  constexpr size_t o_Vt = 35405824;
  constexpr size_t o_x2 = 43794432;                  // 8192*512*4
  constexpr size_t o_gate = 60571648;                // 8192*2304*2

  u16* wqkv = (u16*)(ws + o_wqkv);
  u16* wout = (u16*)(ws + o_wout);
  u16* wgate = (u16*)(ws + o_wgate);
  u16* wup = (u16*)(ws + o_wup);
  u16* wdown = (u16*)(ws + o_wdown);
  u16* h = (u16*)(ws + o_h);
  float* stats = (float*)(ws + o_stats);
  float* cosT = (float*)(ws + o_cos);
  float* sinT = (float*)(ws + o_sin);
  u16* Qb = (u16*)(ws + o_Q);
  u16* Kb = (u16*)(ws + o_K);
  u16* Vt = (u16*)(ws + o_Vt);
  float* x2 = (float*)(ws + o_x2);
  u16* gateb = (u16*)(ws + o_gate);
  u16* attno = h;
  u16* h2 = Qb;

  hipMemsetAsync(stats, 0, 16384, stream);
  cvt_k<<<768, 256, 0, stream>>>(qkv_w, wqkv, 1536 * 512);
  cvt_k<<<256, 256, 0, stream>>>(out_w, wout, 512 * 512);
  cvt_k<<<1152, 256, 0, stream>>>(gate_w, wgate, 2304 * 512);
  cvt_k<<<1152, 256, 0, stream>>>(up_w, wup, 2304 * 512);
  cvt_k<<<1152, 256, 0, stream>>>(down_w, wdown, 512 * 2304);
  ropetab_k<<<512, 256, 0, stream>>>(cosT, sinT);

  rmsnorm_k<<<8192, 256, 0, stream>>>(x, rms1_w, h);
  colsum_k<<<32, 256, 0, stream>>>(h, stats);
  wscalc_k<<<1, 128, 0, stream>>>(stats, cs_w1, cs_w2);

  EpiArgs ea{};
  ea.q = Qb; ea.k = Kb; ea.vt = Vt; ea.cosT = cosT; ea.sinT = sinT;
  gemm_k<1536, 512, 0, 4><<<768, 256, 0, stream>>>(h, wqkv, ea);

  attn_k<<<2048, 128, 0, stream>>>(Qb, Kb, Vt, attno, (const int*)(stats + 2056));

  EpiArgs e2{};
  e2.resid = x; e2.outf = x2;
  gemm_k<512, 512, 1, 8><<<256, 512, 0, stream>>>(attno, wout, e2);

  rmsnorm_k<<<8192, 256, 0, stream>>>(x2, rms2_w, h2);

  gemmgu_k<<<1152, 512, 0, stream>>>(h2, wgate, wup, gateb);

  EpiArgs e5{};
  e5.resid = x2; e5.outf = (float*)d_out;
  gemm_k<512, 2304, 1, 8><<<256, 512, 0, stream>>>(gateb, wdown, e5);

  (void)in_sizes; (void)n_in; (void)out_size; (void)ws_size;
}

// Round 10
// 326.513 us; speedup vs baseline: 1.2490x; 1.2157x over previous
//
#include <hip/hip_runtime.h>

typedef unsigned short u16;
typedef unsigned int   u32;
typedef __attribute__((ext_vector_type(4))) float  f32x4;
typedef __attribute__((ext_vector_type(8))) __bf16 bf16x8;
typedef __attribute__((ext_vector_type(4))) u32    u32x4;
typedef __attribute__((ext_vector_type(2))) u32    u32x2;

#define B_ 4
#define S_ 2048
#define E_ 512
#define H_ 8
#define D_ 64

__device__ __forceinline__ u16 f2bf(float f) {
  union { float f; u32 u; } a; a.f = f;
  u32 r = a.u + 0x7FFFu + ((a.u >> 16) & 1u);   // RNE
  return (u16)(r >> 16);
}
__device__ __forceinline__ float bf2f(u16 u) {
  union { u32 u; float f; } a; a.u = (u32)u << 16;
  return a.f;
}
__device__ __forceinline__ u32 pkbf(float lo, float hi) {  // bf16(lo) | bf16(hi)<<16
  u32 r;
  asm("v_cvt_pk_bf16_f32 %0, %1, %2" : "=v"(r) : "v"(lo), "v"(hi));
  return r;
}

// async global->LDS, 16B per lane; lds ptr wave-uniform (HW adds lane*16)
#define GLOAD16(gp, lp) __builtin_amdgcn_global_load_lds( \
    (const __attribute__((address_space(1))) void*)(gp),  \
    (__attribute__((address_space(3))) void*)(lp), 16, 0, 0)

#define BARRIER() asm volatile("s_barrier" ::: "memory")

// ---------------- fused prep: 5 weight converts + RoPE table ----------------
__global__ __launch_bounds__(256) void prep_k(const float* __restrict__ qkv_w,
                                              const float* __restrict__ out_w,
                                              const float* __restrict__ gate_w,
                                              const float* __restrict__ up_w,
                                              const float* __restrict__ down_w,
                                              u16* __restrict__ wqkv, u16* __restrict__ wout,
                                              u16* __restrict__ wgate, u16* __restrict__ wup,
                                              u16* __restrict__ wdown,
                                              float* __restrict__ ct, float* __restrict__ st) {
  int bid = (int)blockIdx.x;
  const float* s; u16* d; int base;
  if (bid < 768)       { s = qkv_w;  d = wqkv;  base = bid; }
  else if (bid < 1024) { s = out_w;  d = wout;  base = bid - 768; }
  else if (bid < 2176) { s = gate_w; d = wgate; base = bid - 1024; }
  else if (bid < 3328) { s = up_w;   d = wup;   base = bid - 2176; }
  else if (bid < 4480) { s = down_w; d = wdown; base = bid - 3328; }
  else {
    int idx = (bid - 4480) * 256 + threadIdx.x;   // S_*64
    int sp = idx >> 6, j = idx & 63;
    float f = powf(10000.f, -(float)(j & 31) * (1.f / 32.f));
    float ang = (float)sp * f;
    ct[idx] = cosf(ang);
    st[idx] = sinf(ang);
    return;
  }
  int i = (base * 256 + threadIdx.x) * 4;
  f32x4 v = *(const f32x4*)(s + i);
  u32x2 o;
  o.x = pkbf(v[0], v[1]);
  o.y = pkbf(v[2], v[3]);
  *(u32x2*)(d + i) = o;
}

// ---------------- RMSNorm (row of 512), fp32 in -> bf16 out ----------------
__global__ __launch_bounds__(256) void rmsnorm_k(const float* __restrict__ x,
                                                 const float* __restrict__ wv,
                                                 u16* __restrict__ o) {
  const int row = blockIdx.x;
  const int t = threadIdx.x;
  const float* xr = x + (size_t)row * E_;
  float v0 = xr[t], v1 = xr[t + 256];
  float ss = v0 * v0 + v1 * v1;
#pragma unroll
  for (int m = 1; m < 64; m <<= 1) ss += __shfl_xor(ss, m, 64);
  __shared__ float red[4];
  if ((t & 63) == 0) red[t >> 6] = ss;
  __syncthreads();
  float tot = red[0] + red[1] + red[2] + red[3];
  float rms = 1.f / sqrtf(tot * (1.f / (float)E_) + 1e-6f);
  o[(size_t)row * E_ + t]       = f2bf(v0 * rms * wv[t]);
  o[(size_t)row * E_ + t + 256] = f2bf(v1 * rms * wv[t + 256]);
}

// ------------- column sums (xm) + batch sum/sumsq of h -------------
__global__ __launch_bounds__(256) void colsum_k(const u16* __restrict__ h,
                                                float* __restrict__ st) {
  const int b = blockIdx.x >> 3, ck = blockIdx.x & 7;
  const u16* hb = h + ((size_t)b * S_ + ck * 256) * E_;
  const int t = threadIdx.x;
  float a0 = 0, a1 = 0, s = 0, sq = 0;
  for (int r = 0; r < 256; ++r) {
    float v0 = bf2f(hb[(size_t)r * E_ + t]);
    float v1 = bf2f(hb[(size_t)r * E_ + t + 256]);
    a0 += v0; a1 += v1;
    s += v0 + v1; sq += v0 * v0 + v1 * v1;
  }
  atomicAdd(&st[8 + b * E_ + t], a0);
  atomicAdd(&st[8 + b * E_ + t + 256], a1);
#pragma unroll
  for (int m = 1; m < 64; m <<= 1) { s += __shfl_xor(s, m, 64); sq += __shfl_xor(sq, m, 64); }
  if ((t & 63) == 0) { atomicAdd(&st[b], s); atomicAdd(&st[4 + b], sq); }
}

// ------------- complexity -> window size scalar -------------
__global__ __launch_bounds__(128) void wscalc_k(float* __restrict__ st,
                                                const float* __restrict__ w1,
                                                const float* __restrict__ w2) {
  const int j = threadIdx.x;
  __shared__ float comp[4];
  __shared__ float tw[2];
  float dot[4] = {0.f, 0.f, 0.f, 0.f};
  const float* w1r = w1 + (size_t)j * E_;
  for (int e = 0; e < E_; ++e) {
    float wv = w1r[e];
    dot[0] += st[8 + 0 * E_ + e] * wv;
    dot[1] += st[8 + 1 * E_ + e] * wv;
    dot[2] += st[8 + 2 * E_ + e] * wv;
    dot[3] += st[8 + 3 * E_ + e] * wv;
  }
  for (int b = 0; b < 4; ++b) {
    float d = dot[b] * (1.f / (float)S_);
    float si = d / (1.f + __expf(-d));
    float term = si * w2[j];
#pragma unroll
    for (int m = 1; m < 64; m <<= 1) term += __shfl_xor(term, m, 64);
    __syncthreads();
    if ((j & 63) == 0) tw[j >> 6] = term;
    __syncthreads();
    if (j == 0) {
      float pre = tw[0] + tw[1];
      float learned = 1.f / (1.f + __expf(-pre));
      const float n = (float)S_ * (float)E_;
      float sum = st[b], ssq = st[4 + b];
      float var = (ssq - sum * sum / n) / (n - 1.f);
      float vn = 1.f / (1.f + __expf(-(var * 10.f - 5.f)));
      comp[b] = 0.5f * (vn + learned);
    }
    __syncthreads();
  }
  if (j == 0) {
    float mean = 0.25f * (comp[0] + comp[1] + comp[2] + comp[3]);
    float wsf = 256.f + mean * 768.f;
    int v = (int)wsf;
    v = v < 256 ? 256 : (v > S_ ? S_ : v);
    ((int*)st)[2056] = v;
  }
}

// ---------------- 128x128 bf16 GEMM, BK=64, dbuf + counted vmcnt + (row&7) swizzle ----------------
// C = A[M][K] * W[N][K]^T.  EPI: 0 = QKV (RoPE + scatter), 1 = +resid -> f32 out
// 8 waves. LDS rows 128B (64 elem), chunk(16B) index: lds[r][j] = g[r][j ^ (r&7)]
struct EpiArgs {
  u16* q; u16* k; u16* vt;
  const float* cosT; const float* sinT;
  const float* resid; float* outf;
};

template <int N, int K, int EPI>
__global__ __launch_bounds__(512) void gemm_k(const u16* __restrict__ A,
                                              const u16* __restrict__ W,
                                              EpiArgs ea) {
  constexpr int NBN = N / 128;
  __shared__ u16 sA[2][128 * 64];
  __shared__ u16 sB[2][128 * 64];
  const int tid = threadIdx.x;
  const int nwg = (int)gridDim.x;
  const int bid = (int)blockIdx.x;
  const int logical = (bid & 7) * (nwg >> 3) + (bid >> 3);
  const int bm = logical / NBN, bn = logical % NBN;
  const int lane = tid & 63, w = tid >> 6;
  const int g = lane >> 4, c = lane & 15;
  const int wrow = (w >> 1) * 32;
  const int wcol = (w & 1) * 64;

  // staging: wave stages A/B rows w*16..w*16+15 (2 gloads each); lane -> row +lane>>3, chunk lane&7
  // source chunk pre-swizzled: (lane&7) ^ (lane>>3)  [since (q*8+lr)&7 == lr]
  const int lr0 = lane >> 3;
  const int scol = ((lane & 7) ^ lr0) * 8;
  const u16* gA = A + (size_t)(bm * 128 + w * 16 + lr0) * K + scol;
  const u16* gB = W + (size_t)(bn * 128 + w * 16 + lr0) * K + scol;

  f32x4 acc[2][4];
  f32x4 zz = {0.f, 0.f, 0.f, 0.f};
#pragma unroll
  for (int i = 0; i < 2; ++i)
#pragma unroll
    for (int j = 0; j < 4; ++j) acc[i][j] = zz;

  auto stage = [&](int buf, int ko) {
    GLOAD16(gA + ko,                (char*)sA[buf] + (w * 16) * 128);
    GLOAD16(gA + (size_t)8 * K + ko, (char*)sA[buf] + (w * 16 + 8) * 128);
    GLOAD16(gB + ko,                (char*)sB[buf] + (w * 16) * 128);
    GLOAD16(gB + (size_t)8 * K + ko, (char*)sB[buf] + (w * 16 + 8) * 128);
  };

  constexpr int NIT = K / 64;
  stage(0, 0);
  int cur = 0;
  for (int it = 0; it < NIT; ++it) {
    if (it + 1 < NIT) {
      stage(cur ^ 1, (it + 1) * 64);
      asm volatile("s_waitcnt vmcnt(4)" ::: "memory");
    } else {
      asm volatile("s_waitcnt vmcnt(0)" ::: "memory");
    }
    BARRIER();
    const u16* bufA = sA[cur];
    const u16* bufB = sB[cur];
    bf16x8 af[2][2], bfr[4][2];
#pragma unroll
    for (int mi = 0; mi < 2; ++mi) {
      int ar = wrow + mi * 16 + c;
#pragma unroll
      for (int kk = 0; kk < 2; ++kk)
        af[mi][kk] = *(const bf16x8*)&bufA[ar * 64 + (((kk * 4 + g) ^ (ar & 7)) * 8)];
    }
#pragma unroll
    for (int nj = 0; nj < 4; ++nj) {
      int br = wcol + nj * 16 + c;
#pragma unroll
      for (int kk = 0; kk < 2; ++kk)
        bfr[nj][kk] = *(const bf16x8*)&bufB[br * 64 + (((kk * 4 + g) ^ (br & 7)) * 8)];
    }
#pragma unroll
    for (int kk = 0; kk < 2; ++kk)
#pragma unroll
      for (int mi = 0; mi < 2; ++mi)
#pragma unroll
        for (int nj = 0; nj < 4; ++nj)
          acc[mi][nj] = __builtin_amdgcn_mfma_f32_16x16x32_bf16(af[mi][kk], bfr[nj][kk], acc[mi][nj], 0, 0, 0);
    BARRIER();
    cur ^= 1;
  }

#pragma unroll
  for (int mi = 0; mi < 2; ++mi) {
#pragma unroll
    for (int nj = 0; nj < 4; ++nj) {
      const int rowb = bm * 128 + wrow + mi * 16 + 4 * g;
      const int cc = bn * 128 + wcol + nj * 16 + c;
      if constexpr (EPI == 0) {
        const int which = cc >> 9;
        const int hh = (cc >> 6) & 7;
        const int d = cc & 63;
        const int bi = rowb >> 11;
        const int s = rowb & (S_ - 1);
        if (which == 2) {  // V -> transposed [bh][d][s]
          u32x2 pk;
          pk.x = pkbf(acc[mi][nj][0], acc[mi][nj][1]);
          pk.y = pkbf(acc[mi][nj][2], acc[mi][nj][3]);
          *(u32x2*)(ea.vt + (((size_t)(bi * H_ + hh) * D_ + d) * S_ + s)) = pk;
        } else {           // Q/K with interleaved RoPE
          u16* dst = (which == 0 ? ea.q : ea.k) + (((size_t)(bi * H_ + hh) * S_ + s) * D_ + d);
#pragma unroll
          for (int r = 0; r < 4; ++r) {
            float v = acc[mi][nj][r];
            float pv = __shfl_xor(v, 1, 64);
            int si = s + r;
            float cs = ea.cosT[si * 64 + d];
            float sn = ea.sinT[si * 64 + d];
            float o = v * cs + ((d & 1) ? pv : -pv) * sn;
            dst[(size_t)r * D_] = f2bf(o);
          }
        }
      } else {  // EPI 1: +resid -> f32
#pragma unroll
        for (int r = 0; r < 4; ++r) {
          size_t idx = (size_t)(rowb + r) * N + cc;
          ea.outf[idx] = acc[mi][nj][r] + ea.resid[idx];
        }
      }
    }
  }
}

// ---------------- fused gate+up GEMM with silu epilogue (8 waves, dbuf, counted vmcnt) ----------------
__global__ __launch_bounds__(512) void gemmgu_k(const u16* __restrict__ A,
                                                const u16* __restrict__ Wg,
                                                const u16* __restrict__ Wu,
                                                u16* __restrict__ outb) {
  __shared__ u16 sA[2][128 * 32];
  __shared__ u16 sG[2][128 * 32];
  __shared__ u16 sU[2][128 * 32];
  const int tid = threadIdx.x;
  const int nwg = (int)gridDim.x;          // 1152
  const int bid = (int)blockIdx.x;
  const int logical = (bid & 7) * (nwg >> 3) + (bid >> 3);
  const int bm = logical / 18, bn = logical % 18;
  const int lane = tid & 63, w = tid >> 6;
  const int g = lane >> 4, c = lane & 15;
  const int wrow = (w >> 1) * 32;
  const int wcol = (w & 1) * 64;

  const int sr0 = w * 16 + (lane >> 2);
  const int ch0 = (lane & 3) ^ ((sr0 >> 1) & 3);
  const u16* gA = A + (size_t)(bm * 128 + sr0) * 512 + ch0 * 8;
  const u16* gG = Wg + (size_t)(bn * 128 + sr0) * 512 + ch0 * 8;
  const u16* gU = Wu + (size_t)(bn * 128 + sr0) * 512 + ch0 * 8;
  const int lofs = w * 1024;

  f32x4 accg[2][4], accu[2][4];
  f32x4 zz = {0.f, 0.f, 0.f, 0.f};
#pragma unroll
  for (int i = 0; i < 2; ++i)
#pragma unroll
    for (int j = 0; j < 4; ++j) { accg[i][j] = zz; accu[i][j] = zz; }

  auto stage = [&](int buf, int ko) {
    GLOAD16(gA + ko, (char*)sA[buf] + lofs);
    GLOAD16(gG + ko, (char*)sG[buf] + lofs);
    GLOAD16(gU + ko, (char*)sU[buf] + lofs);
  };

  stage(0, 0);
  int cur = 0;
  for (int it = 0; it < 16; ++it) {
    if (it + 1 < 16) {
      stage(cur ^ 1, (it + 1) * 32);
      asm volatile("s_waitcnt vmcnt(3)" ::: "memory");
    } else {
      asm volatile("s_waitcnt vmcnt(0)" ::: "memory");
    }
    BARRIER();
    const u16* bufA = sA[cur];
    const u16* bufG = sG[cur];
    const u16* bufU = sU[cur];
    bf16x8 af[2], bg[4], bu[4];
#pragma unroll
    for (int mi = 0; mi < 2; ++mi) {
      int ar = wrow + mi * 16 + c;
      af[mi] = *(const bf16x8*)&bufA[ar * 32 + ((g ^ ((ar >> 1) & 3)) * 8)];
    }
#pragma unroll
    for (int nj = 0; nj < 4; ++nj) {
      int br = wcol + nj * 16 + c;
      int sw = (g ^ ((br >> 1) & 3)) * 8;
      bg[nj] = *(const bf16x8*)&bufG[br * 32 + sw];
      bu[nj] = *(const bf16x8*)&bufU[br * 32 + sw];
    }
#pragma unroll
    for (int mi = 0; mi < 2; ++mi)
#pragma unroll
      for (int nj = 0; nj < 4; ++nj) {
        accg[mi][nj] = __builtin_amdgcn_mfma_f32_16x16x32_bf16(af[mi], bg[nj], accg[mi][nj], 0, 0, 0);
        accu[mi][nj] = __builtin_amdgcn_mfma_f32_16x16x32_bf16(af[mi], bu[nj], accu[mi][nj], 0, 0, 0);
      }
    BARRIER();
    cur ^= 1;
  }

#pragma unroll
  for (int mi = 0; mi < 2; ++mi) {
#pragma unroll
    for (int nj = 0; nj < 4; ++nj) {
      const int rowb = bm * 128 + wrow + mi * 16 + 4 * g;
      const int cc = bn * 128 + wcol + nj * 16 + c;
#pragma unroll
      for (int r = 0; r < 4; ++r) {
        float gv = accg[mi][nj][r];
        float uv = accu[mi][nj][r];
        float sil = gv / (1.f + __expf(-gv));
        outb[(size_t)(rowb + r) * 2304 + cc] = f2bf(sil * uv);
      }
    }
  }
}

// ---------------- sliding-window flash attention, LDS-staged K/V ----------------
// 1024 blocks x 4 waves; block = (bh, 64-query tile); K/V tiles staged once per block,
// double-buffered; waves predicate compute on their window overlap.
__global__ __launch_bounds__(256) void attn_k(const u16* __restrict__ Qb,
                                              const u16* __restrict__ Kb,
                                              const u16* __restrict__ Vt,
                                              u16* __restrict__ ao,
                                              const int* __restrict__ wsp) {
  __shared__ u16 sK[2][64 * 64];
  __shared__ u16 sV[2][64 * 64];
  const int bid = (int)blockIdx.x;
  const int qt = 31 - (bid >> 5);          // longest-window-first
  const int bh = bid & 31;
  const int b = bh >> 3, h = bh & 7;
  const int tid = threadIdx.x;
  const int w = tid >> 6, lane = tid & 63;
  const int g = lane >> 4, c = lane & 15;
  const int ws = *wsp;
  const int qw = qt * 64 + w * 16;
  const u16* Qh = Qb + (size_t)bh * S_ * D_;
  const u16* Kh = Kb + (size_t)bh * S_ * D_;
  const u16* Vh = Vt + (size_t)bh * D_ * S_;

  bf16x8 qf0 = *(const bf16x8*)(Qh + (qw + c) * D_ + g * 8);
  bf16x8 qf1 = *(const bf16x8*)(Qh + (qw + c) * D_ + 32 + g * 8);

  // staging geometry: wave stages K rows (keys) w*16..+15 and V rows (dims) w*16..+15
  // lane -> row +(lane>>3), chunk lane&7; source chunk = (lane&7)^(lane>>3) [pre-swizzle]
  const int lr0 = lane >> 3;
  const int scol = ((lane & 7) ^ lr0) * 8;
  const u16* gK = Kh + (size_t)(w * 16 + lr0) * D_ + scol;     // + (kb)*D_
  const u16* gV = Vh + (size_t)(w * 16 + lr0) * S_ + scol;     // + kb

  const float SCL = 0.125f * 1.44269504089f;   // d^-0.5 * log2(e)
  float m2 = -3e38f, lsum = 0.f;
  f32x4 O[4];
  f32x4 zz = {0.f, 0.f, 0.f, 0.f};
#pragma unroll
  for (int i = 0; i < 4; ++i) O[i] = zz;

  int lo_w = qw - ws + 1;
  if (lo_w < 0) lo_w = 0;
  int lo_blk = qt * 64 - ws + 1;
  if (lo_blk < 0) lo_blk = 0;
  lo_blk &= ~63;
  const int qhi = qt * 64 + 63;
  const int nkb = (qhi - lo_blk) / 64 + 1;
  const int q = qw + c;

  auto stageKV = [&](int buf, int kb) {
    GLOAD16(gK + (size_t)kb * D_,            (char*)sK[buf] + (w * 16) * 128);
    GLOAD16(gK + (size_t)(kb + 8) * D_,      (char*)sK[buf] + (w * 16 + 8) * 128);
    GLOAD16(gV + kb,                         (char*)sV[buf] + (w * 16) * 128);
    GLOAD16(gV + kb + (size_t)8 * S_,        (char*)sV[buf] + (w * 16 + 8) * 128);
  };

  stageKV(0, lo_blk);
  asm volatile("s_waitcnt vmcnt(0)" ::: "memory");
  BARRIER();
  int cur = 0;
  for (int i = 0; i < nkb; ++i) {
    const int kb = lo_blk + i * 64;
    if (i + 1 < nkb) stageKV(cur ^ 1, kb + 64);
    if (kb <= qw + 15 && kb + 63 >= lo_w) {
      const u16* bK = sK[cur];
      const u16* bV = sV[cur];
      f32x4 st4[4];
      __builtin_amdgcn_s_setprio(1);
#pragma unroll
      for (int t = 0; t < 4; ++t) {
        const int kr = 16 * t + c;
        bf16x8 k0 = *(const bf16x8*)&bK[kr * 64 + ((g ^ (kr & 7)) * 8)];
        bf16x8 k1 = *(const bf16x8*)&bK[kr * 64 + (((4 + g) ^ (kr & 7)) * 8)];
        f32x4 s = zz;
        s = __builtin_amdgcn_mfma_f32_16x16x32_bf16(k0, qf0, s, 0, 0, 0);
        s = __builtin_amdgcn_mfma_f32_16x16x32_bf16(k1, qf1, s, 0, 0, 0);
        st4[t] = s;
      }
      __builtin_amdgcn_s_setprio(0);
      const bool interior = (kb + 63 <= qw) && (kb >= qw + 16 - ws);
      float p[4][4];
      float bm = -3e38f;
      if (interior) {
#pragma unroll
        for (int t = 0; t < 4; ++t)
#pragma unroll
          for (int r = 0; r < 4; ++r) {
            p[t][r] = st4[t][r] * SCL;
            bm = fmaxf(bm, p[t][r]);
          }
      } else {
#pragma unroll
        for (int t = 0; t < 4; ++t)
#pragma unroll
          for (int r = 0; r < 4; ++r) {
            int ki = kb + 16 * t + 4 * g + r;
            float v = st4[t][r] * SCL;
            bool ok = (q >= ki) && (q - ki) < ws;
            p[t][r] = ok ? v : -__builtin_inff();
            bm = fmaxf(bm, p[t][r]);
          }
      }
      bm = fmaxf(bm, __shfl_xor(bm, 16, 64));
      bm = fmaxf(bm, __shfl_xor(bm, 32, 64));
      if (!__all(bm - m2 <= 8.f)) {          // T13 defer-max
        float mnew = fmaxf(m2, bm);
        float al = exp2f(m2 - mnew);
        lsum *= al;
#pragma unroll
        for (int ii = 0; ii < 4; ++ii) O[ii] *= al;
        m2 = mnew;
      }
      float psum = 0.f;
#pragma unroll
      for (int t = 0; t < 4; ++t)
#pragma unroll
        for (int r = 0; r < 4; ++r) {
          p[t][r] = exp2f(p[t][r] - m2);     // masked -> 0
          psum += p[t][r];
        }
      psum += __shfl_xor(psum, 16, 64);
      psum += __shfl_xor(psum, 32, 64);
      lsum += psum;

      u32 pp[4][2];
#pragma unroll
      for (int t = 0; t < 4; ++t) {
        pp[t][0] = pkbf(p[t][0], p[t][1]);
        pp[t][1] = pkbf(p[t][2], p[t][3]);
      }
      const int lA = (g & 1) * 32 + c;
      const int lB = lA + 16;
      const int hi = g >> 1;
      union { bf16x8 v; u32 u[4]; } pf0, pf1;
#pragma unroll
      for (int wi = 0; wi < 2; ++wi) {
        u32 a0 = (u32)__shfl((int)pp[0][wi], lA, 64);
        u32 a1 = (u32)__shfl((int)pp[1][wi], lA, 64);
        u32 a2 = (u32)__shfl((int)pp[2][wi], lA, 64);
        u32 a3 = (u32)__shfl((int)pp[3][wi], lA, 64);
        u32 b0 = (u32)__shfl((int)pp[0][wi], lB, 64);
        u32 b1 = (u32)__shfl((int)pp[1][wi], lB, 64);
        u32 b2 = (u32)__shfl((int)pp[2][wi], lB, 64);
        u32 b3 = (u32)__shfl((int)pp[3][wi], lB, 64);
        pf0.u[wi]     = hi ? a1 : a0;
        pf0.u[2 + wi] = hi ? b1 : b0;
        pf1.u[wi]     = hi ? a3 : a2;
        pf1.u[2 + wi] = hi ? b3 : b2;
      }
      __builtin_amdgcn_s_setprio(1);
#pragma unroll
      for (int dt = 0; dt < 4; ++dt) {
        const int vr = dt * 16 + c;
        bf16x8 v0 = *(const bf16x8*)&bV[vr * 64 + ((g ^ (vr & 7)) * 8)];
        bf16x8 v1 = *(const bf16x8*)&bV[vr * 64 + (((4 + g) ^ (vr & 7)) * 8)];
        O[dt] = __builtin_amdgcn_mfma_f32_16x16x32_bf16(v0, pf0.v, O[dt], 0, 0, 0);
        O[dt] = __builtin_amdgcn_mfma_f32_16x16x32_bf16(v1, pf1.v, O[dt], 0, 0, 0);
      }
      __builtin_amdgcn_s_setprio(0);
    }
    asm volatile("s_waitcnt vmcnt(0)" ::: "memory");
    BARRIER();
    cur ^= 1;
  }

  const float inv = 1.f / lsum;
  u16* orow = ao + ((size_t)(b * S_ + qw + c)) * E_ + h * D_;
#pragma unroll
  for (int dt = 0; dt < 4; ++dt) {
    u32x2 pk;
    pk.x = pkbf(O[dt][0] * inv, O[dt][1] * inv);
    pk.y = pkbf(O[dt][2] * inv, O[dt][3] * inv);
    *(u32x2*)(orow + dt * 16 + 4 * g) = pk;
  }
}

// ---------------- launcher ----------------
extern "C" void kernel_launch(void* const* d_in, const int* in_sizes, int n_in,
                              void* d_out, int out_size, void* d_ws, size_t ws_size,
                              hipStream_t stream) {
  const float* x      = (const float*)d_in[0];
  const float* rms1_w = (const float*)d_in[1];
  const float* rms2_w = (const float*)d_in[2];
  const float* qkv_w  = (const float*)d_in[3];
  const float* out_w  = (const float*)d_in[4];
  const float* cs_w1  = (const float*)d_in[5];
  const float* cs_w2  = (const float*)d_in[6];
  const float* gate_w = (const float*)d_in[7];
  const float* up_w   = (const float*)d_in[8];
  const float* down_w = (const float*)d_in[9];

  char* ws = (char*)d_ws;
  constexpr size_t o_wqkv = 0;
  constexpr size_t o_wout = 1572864;
  constexpr size_t o_wgate = 2097152;
  constexpr size_t o_wup = 4456448;
  constexpr size_t o_wdown = 6815744;
  constexpr size_t o_h = 9175040;
  constexpr size_t o_stats = 17563648;
  constexpr size_t o_cos = 17580032;
  constexpr size_t o_sin = 18104320;
  constexpr size_t o_Q = 18628608;
  constexpr size_t o_K = 27017216;
  constexpr size_t o_Vt = 35405824;
  constexpr size_t o_x2 = 43794432;
  constexpr size_t o_gate = 60571648;

  u16* wqkv = (u16*)(ws + o_wqkv);
  u16* wout = (u16*)(ws + o_wout);
  u16* wgate = (u16*)(ws + o_wgate);
  u16* wup = (u16*)(ws + o_wup);
  u16* wdown = (u16*)(ws + o_wdown);
  u16* h = (u16*)(ws + o_h);
  float* stats = (float*)(ws + o_stats);
  float* cosT = (float*)(ws + o_cos);
  float* sinT = (float*)(ws + o_sin);
  u16* Qb = (u16*)(ws + o_Q);
  u16* Kb = (u16*)(ws + o_K);
  u16* Vt = (u16*)(ws + o_Vt);
  float* x2 = (float*)(ws + o_x2);
  u16* gateb = (u16*)(ws + o_gate);
  u16* attno = h;
  u16* h2 = Qb;

  hipMemsetAsync(stats, 0, 16384, stream);
  prep_k<<<4992, 256, 0, stream>>>(qkv_w, out_w, gate_w, up_w, down_w,
                                   wqkv, wout, wgate, wup, wdown, cosT, sinT);

  rmsnorm_k<<<8192, 256, 0, stream>>>(x, rms1_w, h);
  colsum_k<<<32, 256, 0, stream>>>(h, stats);
  wscalc_k<<<1, 128, 0, stream>>>(stats, cs_w1, cs_w2);

  EpiArgs ea{};
  ea.q = Qb; ea.k = Kb; ea.vt = Vt; ea.cosT = cosT; ea.sinT = sinT;
  gemm_k<1536, 512, 0><<<768, 512, 0, stream>>>(h, wqkv, ea);

  attn_k<<<1024, 256, 0, stream>>>(Qb, Kb, Vt, attno, (const int*)(stats + 2056));

  EpiArgs e2{};
  e2.resid = x; e2.outf = x2;
  gemm_k<512, 512, 1><<<256, 512, 0, stream>>>(attno, wout, e2);

  rmsnorm_k<<<8192, 256, 0, stream>>>(x2, rms2_w, h2);

  gemmgu_k<<<1152, 512, 0, stream>>>(h2, wgate, wup, gateb);

  EpiArgs e5{};
  e5.resid = x2; e5.outf = (float*)d_out;
  gemm_k<512, 2304, 1><<<256, 512, 0, stream>>>(gateb, wdown, e5);

  (void)in_sizes; (void)n_in; (void)out_size; (void)ws_size;
}